// Round 11
// baseline (466.168 us; speedup 1.0000x reference)
//
#include <hip/hip_runtime.h>

#define N_NODES 50000
#define N_EDGES 800000
#define CCH 64
#define N_MIX 14
#define NBUCK 196   // ceil(50000/256)
#define BCAP 6144   // per-bucket edge capacity (mean ~4082)
#define ECHUNK 3125 // 800000 / 256 blocks, exact
#define DBINS 64

typedef __bf16 bf16x8 __attribute__((ext_vector_type(8)));
typedef float floatx4 __attribute__((ext_vector_type(4)));

__device__ __forceinline__ float leaky(float x) {
    return fmaxf(x, 0.2f * x);
}

// ---------------- weight prep --------------------------------------------
__global__ void prep_weights(const float* __restrict__ alphas,
                             const float* __restrict__ gcn_W, const float* __restrict__ gcn_b,
                             const float* __restrict__ sage_Wl, const float* __restrict__ sage_Wr,
                             const float* __restrict__ sage_b, const float* __restrict__ gat_Wp,
                             const float* __restrict__ a_src, const float* __restrict__ a_dst,
                             const float* __restrict__ gat_b,
                             __bf16* __restrict__ Wt, float* __restrict__ bc,
                             float* __restrict__ vs, float* __restrict__ vd) {
    int k = blockIdx.x;
    __shared__ float w[5];
    if (threadIdx.x == 0) {
        float a[5], m = -1e30f, s = 0.f;
        for (int i = 0; i < 5; ++i) { a[i] = alphas[k * 5 + i]; m = fmaxf(m, a[i]); }
        for (int i = 0; i < 5; ++i) { a[i] = __expf(a[i] - m); s += a[i]; }
        for (int i = 0; i < 5; ++i) w[i] = a[i] / s;
    }
    __syncthreads();
    float gamma = (k >= 9) ? 0.25f : 1.0f;
    float w0 = gamma * w[0], w1 = gamma * w[1], w2 = gamma * w[2], w3 = gamma * w[3];
    float idext = (k >= 11) ? 0.25f : 0.f;
    for (int idx = threadIdx.x; idx < 64 * 256; idx += blockDim.x) {
        int c = idx >> 8, j = idx & 255;
        float v;
        if (j < 64)       v = w0 * gcn_W[k * 4096 + j * 64 + c];
        else if (j < 128) v = w1 * sage_Wl[k * 4096 + (j - 64) * 64 + c];
        else if (j < 192) {
            int jj = j - 128;
            v = w1 * sage_Wr[k * 4096 + jj * 64 + c];
            if (jj == c) v += w3 + idext;
        } else {
            v = w2 * gat_Wp[k * 4096 + (j - 192) * 64 + c];
        }
        Wt[(size_t)k * 16384 + idx] = (__bf16)v;
    }
    if (threadIdx.x < 64) {
        int r = threadIdx.x;
        bc[k * 64 + r] = gamma * (w[0] * gcn_b[k * 64 + r] + w[1] * sage_b[k * 64 + r] +
                                  w[2] * gat_b[k * 64 + r]);
        float s1 = 0.f, s2 = 0.f;
        for (int j = 0; j < 64; ++j) {
            float wv_ = gat_Wp[k * 4096 + r * 64 + j];
            s1 += wv_ * a_src[k * 64 + j];
            s2 += wv_ * a_dst[k * 64 + j];
        }
        vs[k * 64 + r] = s1;
        vd[k * 64 + r] = s2;
    }
}

__global__ void prep_scoreV(const float* __restrict__ vs, const float* __restrict__ vd,
                            __bf16* __restrict__ Vph,
                            unsigned km0, unsigned km1, unsigned km2, unsigned km3,
                            unsigned nks) {
    int p = blockIdx.x;
    unsigned km = (p == 0) ? km0 : (p == 1) ? km1 : (p == 2) ? km2 : km3;
    int nk = (nks >> (p * 4)) & 15;
    for (int idx = threadIdx.x; idx < 1024; idx += blockDim.x) {
        int n = idx >> 6, kk = idx & 63;
        int t = n & 7;
        float v = 0.f;
        if (t < nk) {
            int k = (km >> (4 * t)) & 15;
            v = (n < 8) ? vs[k * 64 + kk] : vd[k * 64 + kk];
        }
        Vph[p * 1024 + n * 64 + kk] = (__bf16)v;
    }
}

__global__ void convert_bf16(const float4* __restrict__ src, __bf16* __restrict__ dst, int n4) {
    int i = blockIdx.x * blockDim.x + threadIdx.x;
    if (i < n4) {
        float4 v = src[i];
        dst[i * 4 + 0] = (__bf16)v.x;
        dst[i * 4 + 1] = (__bf16)v.y;
        dst[i * 4 + 2] = (__bf16)v.z;
        dst[i * 4 + 3] = (__bf16)v.w;
    }
}

// ---------------- CSR build via bucket counting sort -----------------------
__global__ __launch_bounds__(256) void bucket_count(const int* __restrict__ ei,
                                                    int* __restrict__ bcount) {
    __shared__ int h[NBUCK];
    for (int i = threadIdx.x; i < NBUCK; i += 256) h[i] = 0;
    __syncthreads();
    int e0 = blockIdx.x * ECHUNK;
    for (int i = threadIdx.x; i < ECHUNK; i += 256)
        atomicAdd(&h[ei[N_EDGES + e0 + i] >> 8], 1);
    __syncthreads();
    for (int i = threadIdx.x; i < NBUCK; i += 256)
        if (h[i]) atomicAdd(&bcount[i], h[i]);
}

__global__ __launch_bounds__(256) void bucket_scan(const int* __restrict__ bcount,
                                                   int* __restrict__ bbase,
                                                   int* __restrict__ row_ptr) {
    __shared__ int s[256];
    int t = threadIdx.x;
    int v = (t < NBUCK) ? bcount[t] : 0;
    s[t] = v;
    __syncthreads();
    for (int o = 1; o < 256; o <<= 1) {
        int t2 = (t >= o) ? s[t - o] : 0;
        __syncthreads();
        s[t] += t2;
        __syncthreads();
    }
    if (t < NBUCK) bbase[t + 1] = s[t];
    if (t == 0) { bbase[0] = 0; row_ptr[N_NODES] = N_EDGES; }
}

__global__ __launch_bounds__(256) void bucket_scatter(const int* __restrict__ ei,
                                                      const int* __restrict__ bbase,
                                                      int* __restrict__ bfill,
                                                      unsigned* __restrict__ pairs) {
    __shared__ int lh[NBUCK], lbase[NBUCK], lcur[NBUCK];
    int tid = threadIdx.x;
    int e0 = blockIdx.x * ECHUNK;
    for (int i = tid; i < NBUCK; i += 256) { lh[i] = 0; lcur[i] = 0; }
    __syncthreads();
    for (int i = tid; i < ECHUNK; i += 256)
        atomicAdd(&lh[ei[N_EDGES + e0 + i] >> 8], 1);
    __syncthreads();
    for (int i = tid; i < NBUCK; i += 256)
        lbase[i] = bbase[i] + ((lh[i] > 0) ? atomicAdd(&bfill[i], lh[i]) : 0);
    __syncthreads();
    for (int i = tid; i < ECHUNK; i += 256) {
        int s = ei[e0 + i];
        int d = ei[N_EDGES + e0 + i];
        int b = d >> 8;
        int pos = atomicAdd(&lcur[b], 1);
        pairs[lbase[b] + pos] = (unsigned)s | ((unsigned)(d & 255) << 16);
    }
}

__global__ __launch_bounds__(256) void bucket_sort(const unsigned* __restrict__ pairs,
                                                   const int* __restrict__ bbase,
                                                   int* __restrict__ row_ptr,
                                                   int* __restrict__ col_idx,
                                                   float* __restrict__ dinv,
                                                   float* __restrict__ cntf) {
    int b = blockIdx.x;
    __shared__ unsigned buf[BCAP];
    __shared__ int hist[256], off[256], cur[256];
    int tid = threadIdx.x;
    hist[tid] = 0;
    __syncthreads();
    int base = bbase[b], cnt = bbase[b + 1] - base;
    if (cnt > BCAP) cnt = BCAP;
    for (int i = tid; i < cnt; i += 256) {
        unsigned pr = pairs[(size_t)base + i];
        buf[i] = pr;
        atomicAdd(&hist[(pr >> 16) & 255], 1);
    }
    __syncthreads();
    int v = hist[tid];
    off[tid] = v;
    __syncthreads();
    for (int o = 1; o < 256; o <<= 1) {
        int t2 = (tid >= o) ? off[tid - o] : 0;
        __syncthreads();
        off[tid] += t2;
        __syncthreads();
    }
    int excl = off[tid] - v;
    int node = b * 256 + tid;
    if (node < N_NODES) {
        row_ptr[node] = base + excl;
        dinv[node] = rsqrtf((float)(v + 1));
        cntf[node] = (float)(v > 0 ? v : 1);
    }
    cur[tid] = excl;
    __syncthreads();
    for (int i = tid; i < cnt; i += 256) {
        unsigned pr = buf[i];
        int ln = (pr >> 16) & 255;
        int pos = atomicAdd(&cur[ln], 1);
        col_idx[base + pos] = (int)(pr & 0xffffu);
    }
}

// ---------------- degree-sorted node permutation ---------------------------
__global__ __launch_bounds__(256) void deg_hist(const int* __restrict__ row_ptr,
                                                int* __restrict__ dh) {
    __shared__ int h[DBINS];
    if (threadIdx.x < DBINS) h[threadIdx.x] = 0;
    __syncthreads();
    int i = blockIdx.x * 256 + threadIdx.x;
    if (i < N_NODES) {
        int d = row_ptr[i + 1] - row_ptr[i];
        atomicAdd(&h[min(d, DBINS - 1)], 1);
    }
    __syncthreads();
    if (threadIdx.x < DBINS && h[threadIdx.x]) atomicAdd(&dh[threadIdx.x], h[threadIdx.x]);
}

__global__ __launch_bounds__(64) void deg_scan(const int* __restrict__ dh,
                                               int* __restrict__ dbase) {
    int t = threadIdx.x;
    int v = dh[t];
    int inc = v;
#pragma unroll
    for (int o = 1; o < 64; o <<= 1) {
        int t2 = __shfl_up(inc, o, 64);
        if (t >= o) inc += t2;
    }
    dbase[t] = inc - v;  // exclusive
}

__global__ __launch_bounds__(256) void deg_scatter(const int* __restrict__ row_ptr,
                                                   const int* __restrict__ dbase,
                                                   int* __restrict__ dfill,
                                                   int* __restrict__ perm) {
    __shared__ int lh[DBINS], lbase[DBINS], lcur[DBINS];
    int tid = threadIdx.x;
    if (tid < DBINS) { lh[tid] = 0; lcur[tid] = 0; }
    __syncthreads();
    int i = blockIdx.x * 256 + tid;
    int d = -1;
    if (i < N_NODES) {
        d = min(row_ptr[i + 1] - row_ptr[i], DBINS - 1);
        atomicAdd(&lh[d], 1);
    }
    __syncthreads();
    if (tid < DBINS) lbase[tid] = dbase[tid] + ((lh[tid] > 0) ? atomicAdd(&dfill[tid], lh[tid]) : 0);
    __syncthreads();
    if (i < N_NODES) {
        int pos = lbase[d] + atomicAdd(&lcur[d], 1);
        perm[pos] = i;
    }
}

// ---------------- MFMA score kernel ----------------------------------------
__global__ __launch_bounds__(256) void score_mfma(const __bf16* __restrict__ hb,
                                                  const __bf16* __restrict__ V,
                                                  float* __restrict__ ssrcS,
                                                  float* __restrict__ sdstS) {
    int tid = threadIdx.x;
    int wave = tid >> 6, lane = tid & 63;
    int quad = lane >> 4, mr = lane & 15;
    int r0 = blockIdx.x * 128 + wave * 32;
    bf16x8 b0 = *(const bf16x8*)(V + mr * 64 + (quad << 3));
    bf16x8 b1 = *(const bf16x8*)(V + mr * 64 + 32 + (quad << 3));
#pragma unroll
    for (int rt = 0; rt < 2; ++rt) {
        int r = r0 + rt * 16 + mr;
        if (r > N_NODES - 1) r = N_NODES - 1;
        bf16x8 a0 = *(const bf16x8*)(hb + (size_t)r * 64 + (quad << 3));
        bf16x8 a1 = *(const bf16x8*)(hb + (size_t)r * 64 + 32 + (quad << 3));
        floatx4 acc = (floatx4){0.f, 0.f, 0.f, 0.f};
        acc = __builtin_amdgcn_mfma_f32_16x16x32_bf16(a0, b0, acc, 0, 0, 0);
        acc = __builtin_amdgcn_mfma_f32_16x16x32_bf16(a1, b1, acc, 0, 0, 0);
#pragma unroll
        for (int reg = 0; reg < 4; ++reg) {
            int row = r0 + rt * 16 + quad * 4 + reg;
            if (row < N_NODES) {
                if (mr < 8) ssrcS[(size_t)row * 8 + mr] = acc[reg];
                else        sdstS[(size_t)row * 8 + (mr - 8)] = acc[reg];
            }
        }
    }
}

// ---------------- fused per-state gather: 8 nodes/wave, degree-sorted ------
// node = perm[...]: all 8 groups in a wave have (near-)equal degree -> no
// masked-lane waste in the edge loops. Self-score-stabilized softmax.
template <int NK>
__global__ __launch_bounds__(128, 4) void fused_gather(
    const __bf16* __restrict__ hb, const int* __restrict__ row_ptr,
    const int* __restrict__ col_idx, const float* __restrict__ dinv,
    const float* __restrict__ cntf, const float* __restrict__ ssrcS,
    const float* __restrict__ sdstS, const int* __restrict__ perm,
    int soff, int doGS,
    __bf16* __restrict__ aggG, __bf16* __restrict__ aggS, __bf16* __restrict__ A) {
    int wid = blockIdx.x * 2 + (threadIdx.x >> 6);
    int lane = threadIdx.x & 63;
    int sub = lane >> 3, ln = lane & 7;
    int node = perm[wid * 8 + sub];
    int beg = row_ptr[node], end = row_ptr[node + 1];

    float sd[NK], selfraw[NK];
    {
        float svv[8], dvl[8];
        float4 a0 = *(const float4*)(ssrcS + (size_t)node * 8 + soff);
        float4 b0 = *(const float4*)(sdstS + (size_t)node * 8 + soff);
        svv[0] = a0.x; svv[1] = a0.y; svv[2] = a0.z; svv[3] = a0.w;
        dvl[0] = b0.x; dvl[1] = b0.y; dvl[2] = b0.z; dvl[3] = b0.w;
        if (NK > 4) {
            float4 a1 = *(const float4*)(ssrcS + (size_t)node * 8 + soff + 4);
            float4 b1 = *(const float4*)(sdstS + (size_t)node * 8 + soff + 4);
            svv[4] = a1.x; svv[5] = a1.y; svv[6] = a1.z; svv[7] = a1.w;
            dvl[4] = b1.x; dvl[5] = b1.y; dvl[6] = b1.z; dvl[7] = b1.w;
        }
#pragma unroll
        for (int t = 0; t < NK; ++t) {
            sd[t] = dvl[t];
            selfraw[t] = leaky(svv[t] + sd[t]);
        }
    }
    bf16x8 hsb = *(const bf16x8*)(hb + (size_t)node * 64 + ln * 8);
    float hs[8];
#pragma unroll
    for (int c = 0; c < 8; ++c) hs[c] = (float)hsb[c];

    float denoml[NK], acc[NK][8], accG[8], accS[8];
#pragma unroll
    for (int c = 0; c < 8; ++c) { accG[c] = 0.f; accS[c] = 0.f; }
#pragma unroll
    for (int t = 0; t < NK; ++t) {
        denoml[t] = 0.f;
#pragma unroll
        for (int c = 0; c < 8; ++c) acc[t][c] = hs[c];  // self term, w_self = 1
    }
    for (int base = beg; base < end; base += 8) {
        int e = base + ln;
        int col = 0;
        float dv = 0.f, wv[NK];
#pragma unroll
        for (int t = 0; t < NK; ++t) wv[t] = 0.f;
        if (e < end) {
            col = col_idx[e];
            dv = dinv[col];
            float svv[8];
            float4 a0 = *(const float4*)(ssrcS + (size_t)col * 8 + soff);
            svv[0] = a0.x; svv[1] = a0.y; svv[2] = a0.z; svv[3] = a0.w;
            if (NK > 4) {
                float4 a1 = *(const float4*)(ssrcS + (size_t)col * 8 + soff + 4);
                svv[4] = a1.x; svv[5] = a1.y; svv[6] = a1.z; svv[7] = a1.w;
            }
#pragma unroll
            for (int t = 0; t < NK; ++t) {
                wv[t] = __expf(leaky(svv[t] + sd[t]) - selfraw[t]);
                denoml[t] += wv[t];
            }
        }
        int jcnt = end - base;
        if (jcnt > 8) jcnt = 8;
        int cs0 = __shfl(col, (sub << 3), 64);
        bf16x8 hx = *(const bf16x8*)(hb + (size_t)cs0 * 64 + ln * 8);
        for (int j = 0; j < jcnt; ++j) {
            bf16x8 hxn;
            if (j + 1 < jcnt) {
                int csn = __shfl(col, (sub << 3) | (j + 1), 64);
                hxn = *(const bf16x8*)(hb + (size_t)csn * 64 + ln * 8);
            }
            int srcl = (sub << 3) | j;
            float dvj = __shfl(dv, srcl, 64);
            float wj[NK];
#pragma unroll
            for (int t = 0; t < NK; ++t) wj[t] = __shfl(wv[t], srcl, 64);
#pragma unroll
            for (int c = 0; c < 8; ++c) {
                float f = (float)hx[c];
                accS[c] += f;
                accG[c] += dvj * f;
#pragma unroll
                for (int t = 0; t < NK; ++t) acc[t][c] += wj[t] * f;
            }
            hx = hxn;
        }
    }
    float denom[NK];
#pragma unroll
    for (int t = 0; t < NK; ++t) {
        float w = denoml[t];
#pragma unroll
        for (int off = 1; off < 8; off <<= 1) w += __shfl_xor(w, off, 64);
        denom[t] = w + 1.0f;
    }

    if (doGS) {
        float dvn = dinv[node];
        float cin = 1.0f / cntf[node];
        bf16x8 og, os;
#pragma unroll
        for (int c = 0; c < 8; ++c) {
            os[c] = (__bf16)(accS[c] * cin);
            og[c] = (__bf16)(dvn * accG[c] + dvn * dvn * hs[c]);
        }
        *(bf16x8*)(aggS + (size_t)node * 64 + ln * 8) = os;
        *(bf16x8*)(aggG + (size_t)node * 64 + ln * 8) = og;
    }
#pragma unroll
    for (int t = 0; t < NK; ++t) {
        bf16x8 oa;
        float inv = 1.0f / denom[t];
#pragma unroll
        for (int c = 0; c < 8; ++c) oa[c] = (__bf16)(acc[t][c] * inv);
        *(bf16x8*)(A + (size_t)t * N_NODES * 64 + (size_t)node * 64 + ln * 8) = oa;
    }
}

// ---------------- MFMA group GEMM ------------------------------------------
// tsel 0..2 -> bf16 state buffer (s2/s3/s4 = the gather shadows), 3 -> fp32 out.
struct GArgs {
    const __bf16* G;
    const __bf16* S;
    const __bf16* Hb;
    const __bf16* A0;
    const __bf16* Wt;
    const float* bc;
    __bf16* tgb[3];
    float* tgf;
    long long slot;
    int nk;
    int initmask;   // bit t: run starting at t does init-write
    int kidx[8];
    int tsel[8];
};

__global__ __launch_bounds__(256) void gemm_group(GArgs a) {
    __shared__ __bf16 Wl[64 * 264];
    int tid = threadIdx.x;
    int wave = tid >> 6, lane = tid & 63;
    int quad = lane >> 4, mr = lane & 15;
    int r0 = blockIdx.x * 128 + wave * 32;
    bf16x8 gf[2][2], sf[2][2], hf[2][2];
#pragma unroll
    for (int rt = 0; rt < 2; ++rt) {
        int r = r0 + rt * 16 + mr;
        if (r > N_NODES - 1) r = N_NODES - 1;
#pragma unroll
        for (int hh = 0; hh < 2; ++hh) {
            int colj = hh * 32 + (quad << 3);
            gf[rt][hh] = *(const bf16x8*)(a.G + (size_t)r * 64 + colj);
            sf[rt][hh] = *(const bf16x8*)(a.S + (size_t)r * 64 + colj);
            hf[rt][hh] = *(const bf16x8*)(a.Hb + (size_t)r * 64 + colj);
        }
    }
    floatx4 acc[2][4];
    float bsum[4];
#pragma unroll
    for (int rt = 0; rt < 2; ++rt)
#pragma unroll
        for (int ct = 0; ct < 4; ++ct) acc[rt][ct] = (floatx4){0.f, 0.f, 0.f, 0.f};
#pragma unroll
    for (int ct = 0; ct < 4; ++ct) bsum[ct] = 0.f;
    int runstart = 0;
    for (int t = 0; t < a.nk; ++t) {
        int k = a.kidx[t];
        __syncthreads();
        {
            const uint4* src = (const uint4*)(a.Wt + (size_t)k * 16384);
            for (int i = tid; i < 2048; i += 256) {
                int row = i >> 5, colj = (i & 31) << 3;
                *(uint4*)&Wl[row * 264 + colj] = src[i];
            }
        }
        __syncthreads();
        const __bf16* Ap = a.A0 + (size_t)t * a.slot;
        bf16x8 af[2][2];
#pragma unroll
        for (int rt = 0; rt < 2; ++rt) {
            int r = r0 + rt * 16 + mr;
            if (r > N_NODES - 1) r = N_NODES - 1;
#pragma unroll
            for (int hh = 0; hh < 2; ++hh)
                af[rt][hh] = *(const bf16x8*)(Ap + (size_t)r * 64 + hh * 32 + (quad << 3));
        }
        const float* bp = a.bc + k * 64;
#pragma unroll
        for (int ct = 0; ct < 4; ++ct) bsum[ct] += bp[ct * 16 + mr];
#pragma unroll
        for (int seg = 0; seg < 4; ++seg) {
#pragma unroll
            for (int hh = 0; hh < 2; ++hh) {
                int kt = seg * 2 + hh;
                bf16x8 a0 = (seg == 0) ? gf[0][hh] : (seg == 1) ? sf[0][hh]
                            : (seg == 2) ? hf[0][hh] : af[0][hh];
                bf16x8 a1 = (seg == 0) ? gf[1][hh] : (seg == 1) ? sf[1][hh]
                            : (seg == 2) ? hf[1][hh] : af[1][hh];
#pragma unroll
                for (int ct = 0; ct < 4; ++ct) {
                    bf16x8 bfr = *(const bf16x8*)&Wl[(ct * 16 + mr) * 264 + (kt << 5) + (quad << 3)];
                    acc[0][ct] = __builtin_amdgcn_mfma_f32_16x16x32_bf16(a0, bfr, acc[0][ct], 0, 0, 0);
                    acc[1][ct] = __builtin_amdgcn_mfma_f32_16x16x32_bf16(a1, bfr, acc[1][ct], 0, 0, 0);
                }
            }
        }
        bool flush = (t == a.nk - 1) || (a.tsel[t + 1] != a.tsel[t]);
        if (flush) {
            int ts = a.tsel[t];
            int init = (a.initmask >> runstart) & 1;
            if (ts < 3) {
                __bf16* tgt = a.tgb[ts];
#pragma unroll
                for (int rt = 0; rt < 2; ++rt) {
#pragma unroll
                    for (int reg = 0; reg < 4; ++reg) {
                        int r = r0 + rt * 16 + quad * 4 + reg;
                        if (r < N_NODES) {
#pragma unroll
                            for (int ct = 0; ct < 4; ++ct) {
                                int c = ct * 16 + mr;
                                float v = acc[rt][ct][reg] + bsum[ct];
                                size_t idx = (size_t)r * 64 + c;
                                if (!init) v += (float)tgt[idx];
                                tgt[idx] = (__bf16)v;
                            }
                        }
                    }
                }
            } else {
                float* tgt = a.tgf;
#pragma unroll
                for (int rt = 0; rt < 2; ++rt) {
#pragma unroll
                    for (int reg = 0; reg < 4; ++reg) {
                        int r = r0 + rt * 16 + quad * 4 + reg;
                        if (r < N_NODES) {
#pragma unroll
                            for (int ct = 0; ct < 4; ++ct) {
                                int c = ct * 16 + mr;
                                float v = acc[rt][ct][reg] + bsum[ct];
                                size_t idx = (size_t)r * 64 + c;
                                if (!init) v += tgt[idx];
                                tgt[idx] = v;
                            }
                        }
                    }
                }
            }
#pragma unroll
            for (int rt = 0; rt < 2; ++rt)
#pragma unroll
                for (int ct = 0; ct < 4; ++ct) acc[rt][ct] = (floatx4){0.f, 0.f, 0.f, 0.f};
#pragma unroll
            for (int ct = 0; ct < 4; ++ct) bsum[ct] = 0.f;
            runstart = t + 1;
        }
    }
}

extern "C" void kernel_launch(void* const* d_in, const int* in_sizes, int n_in,
                              void* d_out, int out_size, void* d_ws, size_t ws_size,
                              hipStream_t stream) {
    const float* x       = (const float*)d_in[0];
    const int*   ei      = (const int*)d_in[1];
    const float* alphas  = (const float*)d_in[2];
    const float* gcn_W   = (const float*)d_in[3];
    const float* gcn_b   = (const float*)d_in[4];
    const float* sage_Wl = (const float*)d_in[5];
    const float* sage_Wr = (const float*)d_in[6];
    const float* sage_b  = (const float*)d_in[7];
    const float* gat_W   = (const float*)d_in[8];
    const float* a_src   = (const float*)d_in[9];
    const float* a_dst   = (const float*)d_in[10];
    const float* gat_b   = (const float*)d_in[11];
    float* out = (float*)d_out;

    char* p = (char*)d_ws;
    auto alloc = [&](size_t bytes) -> char* {
        char* r = p;
        p += (bytes + 255) & ~(size_t)255;
        return r;
    };
    const size_t NCf = (size_t)N_NODES * CCH;
    const size_t NC16 = NCf * 2;
    __bf16* hbuf[4];  // bf16 states: x, s2, s3, s4 (s-buffers ARE the shadows)
    for (int i = 0; i < 4; ++i) hbuf[i] = (__bf16*)alloc(NC16);
    __bf16* aggG = (__bf16*)alloc(NC16);
    __bf16* aggS = (__bf16*)alloc(NC16);
    float* ssrcS = (float*)alloc((size_t)N_NODES * 8 * 4);
    float* sdstS = (float*)alloc((size_t)N_NODES * 8 * 4);
    float* dinv  = (float*)alloc(N_NODES * 4);
    float* cntf  = (float*)alloc(N_NODES * 4);
    int* row_ptr = (int*)alloc((N_NODES + 1) * 4);
    int* col_idx = (int*)alloc((size_t)N_EDGES * 4);
    unsigned* pairs = (unsigned*)alloc((size_t)N_EDGES * 4);
    int* bcount  = (int*)alloc(NBUCK * 4);
    int* bfill   = (int*)alloc(NBUCK * 4);
    int* bbase   = (int*)alloc((NBUCK + 1) * 4);
    int* dh      = (int*)alloc(DBINS * 4);
    int* dbase   = (int*)alloc(DBINS * 4);
    int* dfill   = (int*)alloc(DBINS * 4);
    int* perm    = (int*)alloc(N_NODES * 4);
    __bf16* Wt   = (__bf16*)alloc((size_t)N_MIX * 16384 * 2);
    float* bcv   = (float*)alloc(N_MIX * 64 * 4);
    float* vs    = (float*)alloc(N_MIX * 64 * 4);
    float* vd    = (float*)alloc(N_MIX * 64 * 4);
    __bf16* Vph  = (__bf16*)alloc(4 * 1024 * 2);

    size_t used = (size_t)(p - (char*)d_ws);
    int navail = (int)((ws_size > used) ? ((ws_size - used) / NC16) : 0);
    if (navail < 1) navail = 1;
    if (navail > 8) navail = 8;
    __bf16* Abuf = (__bf16*)alloc((size_t)navail * NC16);

    hipMemsetAsync(bcount, 0, NBUCK * 4, stream);
    hipMemsetAsync(bfill, 0, NBUCK * 4, stream);
    hipMemsetAsync(dh, 0, DBINS * 4, stream);
    hipMemsetAsync(dfill, 0, DBINS * 4, stream);

    prep_weights<<<N_MIX, 256, 0, stream>>>(alphas, gcn_W, gcn_b, sage_Wl, sage_Wr, sage_b,
                                            gat_W, a_src, a_dst, gat_b, Wt, bcv, vs, vd);
    // phase k-sets: {0,1,2,3,5,6,9,10} / {4,7,11} / {8,12} / {13}
    prep_scoreV<<<4, 256, 0, stream>>>(vs, vd, Vph, 0xA9653210u, 0xB74u, 0xC8u, 0xDu, 0x1238u);
    convert_bf16<<<(int)((NCf / 4 + 255) / 256), 256, 0, stream>>>((const float4*)x, hbuf[0],
                                                                   (int)(NCf / 4));
    bucket_count<<<256, 256, 0, stream>>>(ei, bcount);
    bucket_scan<<<1, 256, 0, stream>>>(bcount, bbase, row_ptr);
    bucket_scatter<<<256, 256, 0, stream>>>(ei, bbase, bfill, pairs);
    bucket_sort<<<NBUCK, 256, 0, stream>>>(pairs, bbase, row_ptr, col_idx, dinv, cntf);
    deg_hist<<<NBUCK, 256, 0, stream>>>(row_ptr, dh);
    deg_scan<<<1, 64, 0, stream>>>(dh, dbase);
    deg_scatter<<<NBUCK, 256, 0, stream>>>(row_ptr, dbase, dfill, perm);

    const int AGG_GRID = N_NODES / 16;            // 3125 blocks x 128 thr
    const int GEMM_GRID = (N_NODES + 127) / 128;  // 391

    struct Phase { int nk; int ks[8]; int tg[8]; };
    const Phase ph[4] = {
        {8, {0, 1, 2, 3, 5, 6, 9, 10}, {0, 0, 1, 1, 2, 2, 3, 3}},
        {3, {4, 7, 11, 0, 0, 0, 0, 0}, {1, 2, 3, 0, 0, 0, 0, 0}},
        {2, {8, 12, 0, 0, 0, 0, 0, 0}, {2, 3, 0, 0, 0, 0, 0, 0}},
        {1, {13, 0, 0, 0, 0, 0, 0, 0}, {3, 0, 0, 0, 0, 0, 0, 0}},
    };

    auto launch_gather = [&](int nkk, const __bf16* hb, int soff, int doGS, __bf16* Aslot) {
        switch (nkk) {
            case 8: fused_gather<8><<<AGG_GRID, 128, 0, stream>>>(hb, row_ptr, col_idx, dinv, cntf, ssrcS, sdstS, perm, soff, doGS, aggG, aggS, Aslot); break;
            case 4: fused_gather<4><<<AGG_GRID, 128, 0, stream>>>(hb, row_ptr, col_idx, dinv, cntf, ssrcS, sdstS, perm, soff, doGS, aggG, aggS, Aslot); break;
            case 3: fused_gather<3><<<AGG_GRID, 128, 0, stream>>>(hb, row_ptr, col_idx, dinv, cntf, ssrcS, sdstS, perm, soff, doGS, aggG, aggS, Aslot); break;
            case 2: fused_gather<2><<<AGG_GRID, 128, 0, stream>>>(hb, row_ptr, col_idx, dinv, cntf, ssrcS, sdstS, perm, soff, doGS, aggG, aggS, Aslot); break;
            default: fused_gather<1><<<AGG_GRID, 128, 0, stream>>>(hb, row_ptr, col_idx, dinv, cntf, ssrcS, sdstS, perm, soff, doGS, aggG, aggS, Aslot); break;
        }
    };
    auto make_gemm = [&](const Phase& P, const __bf16* hb, int kstart, int g) {
        GArgs ga;
        ga.G = aggG; ga.S = aggS; ga.Hb = hb; ga.A0 = Abuf;
        ga.Wt = Wt; ga.bc = bcv;
        ga.tgb[0] = hbuf[1]; ga.tgb[1] = hbuf[2]; ga.tgb[2] = hbuf[3];
        ga.tgf = out;
        ga.slot = (long long)NCf;
        ga.nk = g;
        ga.initmask = 0;
        for (int j = 0; j < g; ++j) {
            int k = P.ks[kstart + j];
            ga.kidx[j] = k;
            ga.tsel[j] = P.tg[kstart + j];
            if (k == 0 || k == 2 || k == 5 || k == 9) ga.initmask |= (1 << j);
        }
        for (int j = g; j < 8; ++j) { ga.kidx[j] = 0; ga.tsel[j] = (j > 0) ? ga.tsel[j - 1] : 0; }
        gemm_group<<<GEMM_GRID, 256, 0, stream>>>(ga);
    };

    for (int st = 0; st < 4; ++st) {
        const Phase& P = ph[st];
        const __bf16* hb = hbuf[st];
        score_mfma<<<GEMM_GRID, 256, 0, stream>>>(hb, Vph + st * 1024, ssrcS, sdstS);
        if (navail >= P.nk) {
            // single gather pass (NK = P.nk) into consecutive slots, one gemm
            launch_gather(P.nk, hb, 0, 1, Abuf);
            make_gemm(P, hb, 0, P.nk);
        } else {
            int gs = (navail < 4) ? navail : 4;
            for (int done = 0; done < P.nk;) {
                int g = gs;
                if (g > P.nk - done) g = P.nk - done;
                launch_gather(g, hb, done, (done == 0) ? 1 : 0, Abuf);
                make_gemm(P, hb, done, g);
                done += g;
            }
        }
    }
}

// Round 12
// 443.565 us; speedup vs baseline: 1.0510x; 1.0510x over previous
//
#include <hip/hip_runtime.h>

#define N_NODES 50000
#define N_EDGES 800000
#define CCH 64
#define N_MIX 14
#define NBUCK 196   // ceil(50000/256)
#define BCAP 6144   // per-bucket edge capacity (mean ~4082)
#define ECHUNK 3125 // 800000 / 256 blocks, exact

typedef __bf16 bf16x8 __attribute__((ext_vector_type(8)));
typedef float floatx4 __attribute__((ext_vector_type(4)));

__device__ __forceinline__ float leaky(float x) {
    return fmaxf(x, 0.2f * x);
}

// ---------------- weight prep --------------------------------------------
__global__ void prep_weights(const float* __restrict__ alphas,
                             const float* __restrict__ gcn_W, const float* __restrict__ gcn_b,
                             const float* __restrict__ sage_Wl, const float* __restrict__ sage_Wr,
                             const float* __restrict__ sage_b, const float* __restrict__ gat_Wp,
                             const float* __restrict__ a_src, const float* __restrict__ a_dst,
                             const float* __restrict__ gat_b,
                             __bf16* __restrict__ Wt, float* __restrict__ bc,
                             float* __restrict__ vs, float* __restrict__ vd) {
    int k = blockIdx.x;
    __shared__ float w[5];
    if (threadIdx.x == 0) {
        float a[5], m = -1e30f, s = 0.f;
        for (int i = 0; i < 5; ++i) { a[i] = alphas[k * 5 + i]; m = fmaxf(m, a[i]); }
        for (int i = 0; i < 5; ++i) { a[i] = __expf(a[i] - m); s += a[i]; }
        for (int i = 0; i < 5; ++i) w[i] = a[i] / s;
    }
    __syncthreads();
    float gamma = (k >= 9) ? 0.25f : 1.0f;
    float w0 = gamma * w[0], w1 = gamma * w[1], w2 = gamma * w[2], w3 = gamma * w[3];
    float idext = (k >= 11) ? 0.25f : 0.f;
    for (int idx = threadIdx.x; idx < 64 * 256; idx += blockDim.x) {
        int c = idx >> 8, j = idx & 255;
        float v;
        if (j < 64)       v = w0 * gcn_W[k * 4096 + j * 64 + c];
        else if (j < 128) v = w1 * sage_Wl[k * 4096 + (j - 64) * 64 + c];
        else if (j < 192) {
            int jj = j - 128;
            v = w1 * sage_Wr[k * 4096 + jj * 64 + c];
            if (jj == c) v += w3 + idext;
        } else {
            v = w2 * gat_Wp[k * 4096 + (j - 192) * 64 + c];
        }
        Wt[(size_t)k * 16384 + idx] = (__bf16)v;
    }
    if (threadIdx.x < 64) {
        int r = threadIdx.x;
        bc[k * 64 + r] = gamma * (w[0] * gcn_b[k * 64 + r] + w[1] * sage_b[k * 64 + r] +
                                  w[2] * gat_b[k * 64 + r]);
        float s1 = 0.f, s2 = 0.f;
        for (int j = 0; j < 64; ++j) {
            float wv_ = gat_Wp[k * 4096 + r * 64 + j];
            s1 += wv_ * a_src[k * 64 + j];
            s2 += wv_ * a_dst[k * 64 + j];
        }
        vs[k * 64 + r] = s1;
        vd[k * 64 + r] = s2;
    }
}

__global__ void prep_scoreV(const float* __restrict__ vs, const float* __restrict__ vd,
                            __bf16* __restrict__ Vph,
                            unsigned km0, unsigned km1, unsigned km2, unsigned km3,
                            unsigned nks) {
    int p = blockIdx.x;
    unsigned km = (p == 0) ? km0 : (p == 1) ? km1 : (p == 2) ? km2 : km3;
    int nk = (nks >> (p * 4)) & 15;
    for (int idx = threadIdx.x; idx < 1024; idx += blockDim.x) {
        int n = idx >> 6, kk = idx & 63;
        int t = n & 7;
        float v = 0.f;
        if (t < nk) {
            int k = (km >> (4 * t)) & 15;
            v = (n < 8) ? vs[k * 64 + kk] : vd[k * 64 + kk];
        }
        Vph[p * 1024 + n * 64 + kk] = (__bf16)v;
    }
}

__global__ void convert_bf16(const float4* __restrict__ src, __bf16* __restrict__ dst, int n4) {
    int i = blockIdx.x * blockDim.x + threadIdx.x;
    if (i < n4) {
        float4 v = src[i];
        dst[i * 4 + 0] = (__bf16)v.x;
        dst[i * 4 + 1] = (__bf16)v.y;
        dst[i * 4 + 2] = (__bf16)v.z;
        dst[i * 4 + 3] = (__bf16)v.w;
    }
}

// ---------------- CSR build via bucket counting sort -----------------------
__global__ __launch_bounds__(256) void bucket_count(const int* __restrict__ ei,
                                                    int* __restrict__ bcount) {
    __shared__ int h[NBUCK];
    for (int i = threadIdx.x; i < NBUCK; i += 256) h[i] = 0;
    __syncthreads();
    int e0 = blockIdx.x * ECHUNK;
    for (int i = threadIdx.x; i < ECHUNK; i += 256)
        atomicAdd(&h[ei[N_EDGES + e0 + i] >> 8], 1);
    __syncthreads();
    for (int i = threadIdx.x; i < NBUCK; i += 256)
        if (h[i]) atomicAdd(&bcount[i], h[i]);
}

__global__ __launch_bounds__(256) void bucket_scan(const int* __restrict__ bcount,
                                                   int* __restrict__ bbase,
                                                   int* __restrict__ row_ptr) {
    __shared__ int s[256];
    int t = threadIdx.x;
    int v = (t < NBUCK) ? bcount[t] : 0;
    s[t] = v;
    __syncthreads();
    for (int o = 1; o < 256; o <<= 1) {
        int t2 = (t >= o) ? s[t - o] : 0;
        __syncthreads();
        s[t] += t2;
        __syncthreads();
    }
    if (t < NBUCK) bbase[t + 1] = s[t];
    if (t == 0) { bbase[0] = 0; row_ptr[N_NODES] = N_EDGES; }
}

__global__ __launch_bounds__(256) void bucket_scatter(const int* __restrict__ ei,
                                                      const int* __restrict__ bbase,
                                                      int* __restrict__ bfill,
                                                      unsigned* __restrict__ pairs) {
    __shared__ int lh[NBUCK], lbase[NBUCK], lcur[NBUCK];
    int tid = threadIdx.x;
    int e0 = blockIdx.x * ECHUNK;
    for (int i = tid; i < NBUCK; i += 256) { lh[i] = 0; lcur[i] = 0; }
    __syncthreads();
    for (int i = tid; i < ECHUNK; i += 256)
        atomicAdd(&lh[ei[N_EDGES + e0 + i] >> 8], 1);
    __syncthreads();
    for (int i = tid; i < NBUCK; i += 256)
        lbase[i] = bbase[i] + ((lh[i] > 0) ? atomicAdd(&bfill[i], lh[i]) : 0);
    __syncthreads();
    for (int i = tid; i < ECHUNK; i += 256) {
        int s = ei[e0 + i];
        int d = ei[N_EDGES + e0 + i];
        int b = d >> 8;
        int pos = atomicAdd(&lcur[b], 1);
        pairs[lbase[b] + pos] = (unsigned)s | ((unsigned)(d & 255) << 16);
    }
}

// Also emits the bucket-local degree-sorted permutation: nodes of each
// 256-node bucket, ranked by degree -> waves of 8 get uniform trip counts
// while memory locality stays within the 256-node window.
__global__ __launch_bounds__(256) void bucket_sort(const unsigned* __restrict__ pairs,
                                                   const int* __restrict__ bbase,
                                                   int* __restrict__ row_ptr,
                                                   int* __restrict__ col_idx,
                                                   float* __restrict__ dinv,
                                                   float* __restrict__ cntf,
                                                   int* __restrict__ perm) {
    int b = blockIdx.x;
    __shared__ unsigned buf[BCAP];
    __shared__ int hist[256], off[256], cur[256];
    __shared__ int dh2[64], dbase2[64], dcur2[64];
    int tid = threadIdx.x;
    hist[tid] = 0;
    if (tid < 64) { dh2[tid] = 0; dcur2[tid] = 0; }
    __syncthreads();
    int base = bbase[b], cnt = bbase[b + 1] - base;
    if (cnt > BCAP) cnt = BCAP;
    for (int i = tid; i < cnt; i += 256) {
        unsigned pr = pairs[(size_t)base + i];
        buf[i] = pr;
        atomicAdd(&hist[(pr >> 16) & 255], 1);
    }
    __syncthreads();
    int v = hist[tid];
    off[tid] = v;
    __syncthreads();
    for (int o = 1; o < 256; o <<= 1) {
        int t2 = (tid >= o) ? off[tid - o] : 0;
        __syncthreads();
        off[tid] += t2;
        __syncthreads();
    }
    int excl = off[tid] - v;
    int node = b * 256 + tid;
    int dbin = -1;
    if (node < N_NODES) {
        row_ptr[node] = base + excl;
        dinv[node] = rsqrtf((float)(v + 1));
        cntf[node] = (float)(v > 0 ? v : 1);
        dbin = min(v, 63);
        atomicAdd(&dh2[dbin], 1);
    }
    cur[tid] = excl;
    __syncthreads();
    if (tid < 64) {
        int val = dh2[tid];
        int inc = val;
#pragma unroll
        for (int o = 1; o < 64; o <<= 1) {
            int t2 = __shfl_up(inc, o, 64);
            if (tid >= o) inc += t2;
        }
        dbase2[tid] = inc - val;
    }
    __syncthreads();
    if (node < N_NODES) {
        int pos = dbase2[dbin] + atomicAdd(&dcur2[dbin], 1);
        perm[b * 256 + pos] = node;
    }
    for (int i = tid; i < cnt; i += 256) {
        unsigned pr = buf[i];
        int ln = (pr >> 16) & 255;
        int pos = atomicAdd(&cur[ln], 1);
        col_idx[base + pos] = (int)(pr & 0xffffu);
    }
}

// ---------------- MFMA score kernel ----------------------------------------
__global__ __launch_bounds__(256) void score_mfma(const __bf16* __restrict__ hb,
                                                  const __bf16* __restrict__ V,
                                                  float* __restrict__ ssrcS,
                                                  float* __restrict__ sdstS) {
    int tid = threadIdx.x;
    int wave = tid >> 6, lane = tid & 63;
    int quad = lane >> 4, mr = lane & 15;
    int r0 = blockIdx.x * 128 + wave * 32;
    bf16x8 b0 = *(const bf16x8*)(V + mr * 64 + (quad << 3));
    bf16x8 b1 = *(const bf16x8*)(V + mr * 64 + 32 + (quad << 3));
#pragma unroll
    for (int rt = 0; rt < 2; ++rt) {
        int r = r0 + rt * 16 + mr;
        if (r > N_NODES - 1) r = N_NODES - 1;
        bf16x8 a0 = *(const bf16x8*)(hb + (size_t)r * 64 + (quad << 3));
        bf16x8 a1 = *(const bf16x8*)(hb + (size_t)r * 64 + 32 + (quad << 3));
        floatx4 acc = (floatx4){0.f, 0.f, 0.f, 0.f};
        acc = __builtin_amdgcn_mfma_f32_16x16x32_bf16(a0, b0, acc, 0, 0, 0);
        acc = __builtin_amdgcn_mfma_f32_16x16x32_bf16(a1, b1, acc, 0, 0, 0);
#pragma unroll
        for (int reg = 0; reg < 4; ++reg) {
            int row = r0 + rt * 16 + quad * 4 + reg;
            if (row < N_NODES) {
                if (mr < 8) ssrcS[(size_t)row * 8 + mr] = acc[reg];
                else        sdstS[(size_t)row * 8 + (mr - 8)] = acc[reg];
            }
        }
    }
}

// ---------------- fused per-state gather: 8 nodes/wave ---------------------
// node = perm[...] (bucket-local degree rank). Self-score-stabilized softmax.
// NK=8 uses min-waves=2 (256-VGPR budget, no spill); NK<=4 uses 4.
template <int NK>
__global__ __launch_bounds__(128, (NK > 4 ? 2 : 4)) void fused_gather(
    const __bf16* __restrict__ hb, const int* __restrict__ row_ptr,
    const int* __restrict__ col_idx, const float* __restrict__ dinv,
    const float* __restrict__ cntf, const float* __restrict__ ssrcS,
    const float* __restrict__ sdstS, const int* __restrict__ perm,
    int soff, int doGS,
    __bf16* __restrict__ aggG, __bf16* __restrict__ aggS, __bf16* __restrict__ A) {
    int wid = blockIdx.x * 2 + (threadIdx.x >> 6);
    int lane = threadIdx.x & 63;
    int sub = lane >> 3, ln = lane & 7;
    int node = perm[wid * 8 + sub];
    int beg = row_ptr[node], end = row_ptr[node + 1];

    float sd[NK], selfraw[NK];
    {
        float svv[8], dvl[8];
        float4 a0 = *(const float4*)(ssrcS + (size_t)node * 8 + soff);
        float4 b0 = *(const float4*)(sdstS + (size_t)node * 8 + soff);
        svv[0] = a0.x; svv[1] = a0.y; svv[2] = a0.z; svv[3] = a0.w;
        dvl[0] = b0.x; dvl[1] = b0.y; dvl[2] = b0.z; dvl[3] = b0.w;
        if (NK > 4) {
            float4 a1 = *(const float4*)(ssrcS + (size_t)node * 8 + soff + 4);
            float4 b1 = *(const float4*)(sdstS + (size_t)node * 8 + soff + 4);
            svv[4] = a1.x; svv[5] = a1.y; svv[6] = a1.z; svv[7] = a1.w;
            dvl[4] = b1.x; dvl[5] = b1.y; dvl[6] = b1.z; dvl[7] = b1.w;
        }
#pragma unroll
        for (int t = 0; t < NK; ++t) {
            sd[t] = dvl[t];
            selfraw[t] = leaky(svv[t] + sd[t]);
        }
    }
    bf16x8 hsb = *(const bf16x8*)(hb + (size_t)node * 64 + ln * 8);
    float hs[8];
#pragma unroll
    for (int c = 0; c < 8; ++c) hs[c] = (float)hsb[c];

    float denoml[NK], acc[NK][8], accG[8], accS[8];
#pragma unroll
    for (int c = 0; c < 8; ++c) { accG[c] = 0.f; accS[c] = 0.f; }
#pragma unroll
    for (int t = 0; t < NK; ++t) {
        denoml[t] = 0.f;
#pragma unroll
        for (int c = 0; c < 8; ++c) acc[t][c] = hs[c];  // self term, w_self = 1
    }
    for (int base = beg; base < end; base += 8) {
        int e = base + ln;
        int col = 0;
        float dv = 0.f, wv[NK];
#pragma unroll
        for (int t = 0; t < NK; ++t) wv[t] = 0.f;
        if (e < end) {
            col = col_idx[e];
            dv = dinv[col];
            float svv[8];
            float4 a0 = *(const float4*)(ssrcS + (size_t)col * 8 + soff);
            svv[0] = a0.x; svv[1] = a0.y; svv[2] = a0.z; svv[3] = a0.w;
            if (NK > 4) {
                float4 a1 = *(const float4*)(ssrcS + (size_t)col * 8 + soff + 4);
                svv[4] = a1.x; svv[5] = a1.y; svv[6] = a1.z; svv[7] = a1.w;
            }
#pragma unroll
            for (int t = 0; t < NK; ++t) {
                wv[t] = __expf(leaky(svv[t] + sd[t]) - selfraw[t]);
                denoml[t] += wv[t];
            }
        }
        int jcnt = end - base;
        if (jcnt > 8) jcnt = 8;
        int cs0 = __shfl(col, (sub << 3), 64);
        bf16x8 hx = *(const bf16x8*)(hb + (size_t)cs0 * 64 + ln * 8);
        for (int j = 0; j < jcnt; ++j) {
            bf16x8 hxn;
            if (j + 1 < jcnt) {
                int csn = __shfl(col, (sub << 3) | (j + 1), 64);
                hxn = *(const bf16x8*)(hb + (size_t)csn * 64 + ln * 8);
            }
            int srcl = (sub << 3) | j;
            float dvj = __shfl(dv, srcl, 64);
            float wj[NK];
#pragma unroll
            for (int t = 0; t < NK; ++t) wj[t] = __shfl(wv[t], srcl, 64);
#pragma unroll
            for (int c = 0; c < 8; ++c) {
                float f = (float)hx[c];
                accS[c] += f;
                accG[c] += dvj * f;
#pragma unroll
                for (int t = 0; t < NK; ++t) acc[t][c] += wj[t] * f;
            }
            hx = hxn;
        }
    }
    float denom[NK];
#pragma unroll
    for (int t = 0; t < NK; ++t) {
        float w = denoml[t];
#pragma unroll
        for (int off = 1; off < 8; off <<= 1) w += __shfl_xor(w, off, 64);
        denom[t] = w + 1.0f;
    }

    if (doGS) {
        float dvn = dinv[node];
        float cin = 1.0f / cntf[node];
        bf16x8 og, os;
#pragma unroll
        for (int c = 0; c < 8; ++c) {
            os[c] = (__bf16)(accS[c] * cin);
            og[c] = (__bf16)(dvn * accG[c] + dvn * dvn * hs[c]);
        }
        *(bf16x8*)(aggS + (size_t)node * 64 + ln * 8) = os;
        *(bf16x8*)(aggG + (size_t)node * 64 + ln * 8) = og;
    }
#pragma unroll
    for (int t = 0; t < NK; ++t) {
        bf16x8 oa;
        float inv = 1.0f / denom[t];
#pragma unroll
        for (int c = 0; c < 8; ++c) oa[c] = (__bf16)(acc[t][c] * inv);
        *(bf16x8*)(A + (size_t)t * N_NODES * 64 + (size_t)node * 64 + ln * 8) = oa;
    }
}

// ---------------- MFMA group GEMM: 64 rows/block (16/wave), grid 782 -------
// tsel 0..2 -> bf16 state buffer (s2/s3/s4 = the gather inputs), 3 -> fp32 out.
struct GArgs {
    const __bf16* G;
    const __bf16* S;
    const __bf16* Hb;
    const __bf16* A0;
    const __bf16* Wt;
    const float* bc;
    __bf16* tgb[3];
    float* tgf;
    long long slot;
    int nk;
    int initmask;   // bit t: run starting at t does init-write
    int kidx[8];
    int tsel[8];
};

__global__ __launch_bounds__(256) void gemm_group(GArgs a) {
    __shared__ __bf16 Wl[64 * 264];
    int tid = threadIdx.x;
    int wave = tid >> 6, lane = tid & 63;
    int quad = lane >> 4, mr = lane & 15;
    int r0 = blockIdx.x * 64 + wave * 16;
    int r = r0 + mr;
    if (r > N_NODES - 1) r = N_NODES - 1;
    bf16x8 gf[2], sf[2], hf[2];
#pragma unroll
    for (int hh = 0; hh < 2; ++hh) {
        int colj = hh * 32 + (quad << 3);
        gf[hh] = *(const bf16x8*)(a.G + (size_t)r * 64 + colj);
        sf[hh] = *(const bf16x8*)(a.S + (size_t)r * 64 + colj);
        hf[hh] = *(const bf16x8*)(a.Hb + (size_t)r * 64 + colj);
    }
    floatx4 acc[4];
    float bsum[4];
#pragma unroll
    for (int ct = 0; ct < 4; ++ct) { acc[ct] = (floatx4){0.f, 0.f, 0.f, 0.f}; bsum[ct] = 0.f; }
    int runstart = 0;
    for (int t = 0; t < a.nk; ++t) {
        int k = a.kidx[t];
        __syncthreads();
        {
            const uint4* src = (const uint4*)(a.Wt + (size_t)k * 16384);
            for (int i = tid; i < 2048; i += 256) {
                int row = i >> 5, colj = (i & 31) << 3;
                *(uint4*)&Wl[row * 264 + colj] = src[i];
            }
        }
        __syncthreads();
        const __bf16* Ap = a.A0 + (size_t)t * a.slot;
        bf16x8 af[2];
#pragma unroll
        for (int hh = 0; hh < 2; ++hh)
            af[hh] = *(const bf16x8*)(Ap + (size_t)r * 64 + hh * 32 + (quad << 3));
        const float* bp = a.bc + k * 64;
#pragma unroll
        for (int ct = 0; ct < 4; ++ct) bsum[ct] += bp[ct * 16 + mr];
#pragma unroll
        for (int seg = 0; seg < 4; ++seg) {
#pragma unroll
            for (int hh = 0; hh < 2; ++hh) {
                int kt = seg * 2 + hh;
                bf16x8 a0 = (seg == 0) ? gf[hh] : (seg == 1) ? sf[hh]
                            : (seg == 2) ? hf[hh] : af[hh];
#pragma unroll
                for (int ct = 0; ct < 4; ++ct) {
                    bf16x8 bfr = *(const bf16x8*)&Wl[(ct * 16 + mr) * 264 + (kt << 5) + (quad << 3)];
                    acc[ct] = __builtin_amdgcn_mfma_f32_16x16x32_bf16(a0, bfr, acc[ct], 0, 0, 0);
                }
            }
        }
        bool flush = (t == a.nk - 1) || (a.tsel[t + 1] != a.tsel[t]);
        if (flush) {
            int ts = a.tsel[t];
            int init = (a.initmask >> runstart) & 1;
            if (ts < 3) {
                __bf16* tgt = a.tgb[ts];
#pragma unroll
                for (int reg = 0; reg < 4; ++reg) {
                    int row = r0 + quad * 4 + reg;
                    if (row < N_NODES) {
#pragma unroll
                        for (int ct = 0; ct < 4; ++ct) {
                            int c = ct * 16 + mr;
                            float v = acc[ct][reg] + bsum[ct];
                            size_t idx = (size_t)row * 64 + c;
                            if (!init) v += (float)tgt[idx];
                            tgt[idx] = (__bf16)v;
                        }
                    }
                }
            } else {
                float* tgt = a.tgf;
#pragma unroll
                for (int reg = 0; reg < 4; ++reg) {
                    int row = r0 + quad * 4 + reg;
                    if (row < N_NODES) {
#pragma unroll
                        for (int ct = 0; ct < 4; ++ct) {
                            int c = ct * 16 + mr;
                            float v = acc[ct][reg] + bsum[ct];
                            size_t idx = (size_t)row * 64 + c;
                            if (!init) v += tgt[idx];
                            tgt[idx] = v;
                        }
                    }
                }
            }
#pragma unroll
            for (int ct = 0; ct < 4; ++ct) { acc[ct] = (floatx4){0.f, 0.f, 0.f, 0.f}; bsum[ct] = 0.f; }
            runstart = t + 1;
        }
    }
}

extern "C" void kernel_launch(void* const* d_in, const int* in_sizes, int n_in,
                              void* d_out, int out_size, void* d_ws, size_t ws_size,
                              hipStream_t stream) {
    const float* x       = (const float*)d_in[0];
    const int*   ei      = (const int*)d_in[1];
    const float* alphas  = (const float*)d_in[2];
    const float* gcn_W   = (const float*)d_in[3];
    const float* gcn_b   = (const float*)d_in[4];
    const float* sage_Wl = (const float*)d_in[5];
    const float* sage_Wr = (const float*)d_in[6];
    const float* sage_b  = (const float*)d_in[7];
    const float* gat_W   = (const float*)d_in[8];
    const float* a_src   = (const float*)d_in[9];
    const float* a_dst   = (const float*)d_in[10];
    const float* gat_b   = (const float*)d_in[11];
    float* out = (float*)d_out;

    char* p = (char*)d_ws;
    auto alloc = [&](size_t bytes) -> char* {
        char* r = p;
        p += (bytes + 255) & ~(size_t)255;
        return r;
    };
    const size_t NCf = (size_t)N_NODES * CCH;
    const size_t NC16 = NCf * 2;
    __bf16* hbuf[4];  // bf16 states: x, s2, s3, s4
    for (int i = 0; i < 4; ++i) hbuf[i] = (__bf16*)alloc(NC16);
    __bf16* aggG = (__bf16*)alloc(NC16);
    __bf16* aggS = (__bf16*)alloc(NC16);
    float* ssrcS = (float*)alloc((size_t)N_NODES * 8 * 4);
    float* sdstS = (float*)alloc((size_t)N_NODES * 8 * 4);
    float* dinv  = (float*)alloc(N_NODES * 4);
    float* cntf  = (float*)alloc(N_NODES * 4);
    int* row_ptr = (int*)alloc((N_NODES + 1) * 4);
    int* col_idx = (int*)alloc((size_t)N_EDGES * 4);
    unsigned* pairs = (unsigned*)alloc((size_t)N_EDGES * 4);
    int* bcount  = (int*)alloc(NBUCK * 4);
    int* bfill   = (int*)alloc(NBUCK * 4);
    int* bbase   = (int*)alloc((NBUCK + 1) * 4);
    int* perm    = (int*)alloc(N_NODES * 4);
    __bf16* Wt   = (__bf16*)alloc((size_t)N_MIX * 16384 * 2);
    float* bcv   = (float*)alloc(N_MIX * 64 * 4);
    float* vs    = (float*)alloc(N_MIX * 64 * 4);
    float* vd    = (float*)alloc(N_MIX * 64 * 4);
    __bf16* Vph  = (__bf16*)alloc(4 * 1024 * 2);

    size_t used = (size_t)(p - (char*)d_ws);
    int navail = (int)((ws_size > used) ? ((ws_size - used) / NC16) : 0);
    if (navail < 1) navail = 1;
    if (navail > 8) navail = 8;
    __bf16* Abuf = (__bf16*)alloc((size_t)navail * NC16);

    hipMemsetAsync(bcount, 0, NBUCK * 4, stream);
    hipMemsetAsync(bfill, 0, NBUCK * 4, stream);

    prep_weights<<<N_MIX, 256, 0, stream>>>(alphas, gcn_W, gcn_b, sage_Wl, sage_Wr, sage_b,
                                            gat_W, a_src, a_dst, gat_b, Wt, bcv, vs, vd);
    // phase k-sets: {0,1,2,3,5,6,9,10} / {4,7,11} / {8,12} / {13}
    prep_scoreV<<<4, 256, 0, stream>>>(vs, vd, Vph, 0xA9653210u, 0xB74u, 0xC8u, 0xDu, 0x1238u);
    convert_bf16<<<(int)((NCf / 4 + 255) / 256), 256, 0, stream>>>((const float4*)x, hbuf[0],
                                                                   (int)(NCf / 4));
    bucket_count<<<256, 256, 0, stream>>>(ei, bcount);
    bucket_scan<<<1, 256, 0, stream>>>(bcount, bbase, row_ptr);
    bucket_scatter<<<256, 256, 0, stream>>>(ei, bbase, bfill, pairs);
    bucket_sort<<<NBUCK, 256, 0, stream>>>(pairs, bbase, row_ptr, col_idx, dinv, cntf, perm);

    const int AGG_GRID = N_NODES / 16;             // 3125 blocks x 128 thr
    const int SCORE_GRID = (N_NODES + 127) / 128;  // 391
    const int GEMM_GRID = (N_NODES + 63) / 64;     // 782

    struct Phase { int nk; int ks[8]; int tg[8]; };
    const Phase ph[4] = {
        {8, {0, 1, 2, 3, 5, 6, 9, 10}, {0, 0, 1, 1, 2, 2, 3, 3}},
        {3, {4, 7, 11, 0, 0, 0, 0, 0}, {1, 2, 3, 0, 0, 0, 0, 0}},
        {2, {8, 12, 0, 0, 0, 0, 0, 0}, {2, 3, 0, 0, 0, 0, 0, 0}},
        {1, {13, 0, 0, 0, 0, 0, 0, 0}, {3, 0, 0, 0, 0, 0, 0, 0}},
    };

    auto launch_gather = [&](int nkk, const __bf16* hb, int soff, int doGS, __bf16* Aslot) {
        switch (nkk) {
            case 8: fused_gather<8><<<AGG_GRID, 128, 0, stream>>>(hb, row_ptr, col_idx, dinv, cntf, ssrcS, sdstS, perm, soff, doGS, aggG, aggS, Aslot); break;
            case 4: fused_gather<4><<<AGG_GRID, 128, 0, stream>>>(hb, row_ptr, col_idx, dinv, cntf, ssrcS, sdstS, perm, soff, doGS, aggG, aggS, Aslot); break;
            case 3: fused_gather<3><<<AGG_GRID, 128, 0, stream>>>(hb, row_ptr, col_idx, dinv, cntf, ssrcS, sdstS, perm, soff, doGS, aggG, aggS, Aslot); break;
            case 2: fused_gather<2><<<AGG_GRID, 128, 0, stream>>>(hb, row_ptr, col_idx, dinv, cntf, ssrcS, sdstS, perm, soff, doGS, aggG, aggS, Aslot); break;
            default: fused_gather<1><<<AGG_GRID, 128, 0, stream>>>(hb, row_ptr, col_idx, dinv, cntf, ssrcS, sdstS, perm, soff, doGS, aggG, aggS, Aslot); break;
        }
    };
    auto make_gemm = [&](const Phase& P, const __bf16* hb, int kstart, int g) {
        GArgs ga;
        ga.G = aggG; ga.S = aggS; ga.Hb = hb; ga.A0 = Abuf;
        ga.Wt = Wt; ga.bc = bcv;
        ga.tgb[0] = hbuf[1]; ga.tgb[1] = hbuf[2]; ga.tgb[2] = hbuf[3];
        ga.tgf = out;
        ga.slot = (long long)NCf;
        ga.nk = g;
        ga.initmask = 0;
        for (int j = 0; j < g; ++j) {
            int k = P.ks[kstart + j];
            ga.kidx[j] = k;
            ga.tsel[j] = P.tg[kstart + j];
            if (k == 0 || k == 2 || k == 5 || k == 9) ga.initmask |= (1 << j);
        }
        for (int j = g; j < 8; ++j) { ga.kidx[j] = 0; ga.tsel[j] = (j > 0) ? ga.tsel[j - 1] : 0; }
        gemm_group<<<GEMM_GRID, 256, 0, stream>>>(ga);
    };

    for (int st = 0; st < 4; ++st) {
        const Phase& P = ph[st];
        const __bf16* hb = hbuf[st];
        score_mfma<<<SCORE_GRID, 256, 0, stream>>>(hb, Vph + st * 1024, ssrcS, sdstS);
        if (navail >= P.nk) {
            launch_gather(P.nk, hb, 0, 1, Abuf);
            make_gemm(P, hb, 0, P.nk);
        } else {
            int gs = (navail < 4) ? navail : 4;
            for (int done = 0; done < P.nk;) {
                int g = gs;
                if (g > P.nk - done) g = P.nk - done;
                launch_gather(g, hb, done, (done == 0) ? 1 : 0, Abuf);
                make_gemm(P, hb, done, g);
                done += g;
            }
        }
    }
}